// Round 2
// baseline (91.903 us; speedup 1.0000x reference)
//
#include <hip/hip_runtime.h>

// GatingRouting via piecewise-linear collapse:
//   logit_k(o) = b2_k + sum_j relu(w1_j*o/150 + b1_j) * W2[j,k]  is piecewise
//   LINEAR in o (<=64 breakpoints). Kernel A builds a 4096-cell table over
//   [0,150]: per cell the line (c_k, d_k) using the relu-active set at the
//   cell center. Kernel B: per row -> cell -> 3 fma -> softmax -> blend.
//   Cells crossed by a breakpoint incur |w1*W2|/150 * halfcell ~ 1e-3 logit
//   error -> ~5e-4 output error, well under the 2e-2 threshold.

#define HIDDEN 64
constexpr int   CELLS = 4096;
constexpr float MAXO  = 150.0f;
constexpr int   R     = 4;    // rows per thread (kernel B)
constexpr int   BLOCK = 256;

// LUT layout: lut[2*cell]   = (c0, d0, c1, d1)
//             lut[2*cell+1] = (c2, d2, 0,  0)
__global__ __launch_bounds__(256) void build_lut_kernel(
    const float* __restrict__ W1, const float* __restrict__ b1,
    const float* __restrict__ W2, const float* __restrict__ b2,
    float4* __restrict__ lut)
{
    const int cell = blockIdx.x * blockDim.x + threadIdx.x;
    if (cell >= CELLS) return;
    const float oc = ((float)cell + 0.5f) * (MAXO / (float)CELLS);
    const float x  = oc * (1.0f / MAXO);

    float c0 = b2[0], c1 = b2[1], c2 = b2[2];
    float d0 = 0.f,   d1 = 0.f,   d2 = 0.f;
    for (int j = 0; j < HIDDEN; j++) {
        const float w   = W1[j];
        const float b   = b1[j];
        const float pre = fmaf(x, w, b);
        if (pre > 0.0f) {
            const float ws  = w * (1.0f / MAXO);  // slope contribution per unit o
            const float w20 = W2[3 * j], w21 = W2[3 * j + 1], w22 = W2[3 * j + 2];
            c0 = fmaf(b, w20, c0);  d0 = fmaf(ws, w20, d0);
            c1 = fmaf(b, w21, c1);  d1 = fmaf(ws, w21, d1);
            c2 = fmaf(b, w22, c2);  d2 = fmaf(ws, w22, d2);
        }
    }
    lut[2 * cell]     = make_float4(c0, d0, c1, d1);
    lut[2 * cell + 1] = make_float4(c2, d2, 0.f, 0.f);
}

__global__ __launch_bounds__(BLOCK) void gating_lut_kernel(
    const float* __restrict__ o_batch,
    const float4* __restrict__ lut,
    float* __restrict__ out)
{
    const long long base =
        (long long)blockIdx.x * (BLOCK * R) + (long long)threadIdx.x * R;

    // 4 contiguous rows per thread: one aligned float4 load
    const float4 o4 = *(const float4*)(o_batch + base);
    const float o[R] = {o4.x, o4.y, o4.z, o4.w};

    // Issue all LUT loads up front (scattered 32B reads, L2-resident table)
    float4 p[R], q[R];
#pragma unroll
    for (int r = 0; r < R; r++) {
        int cell = (int)(o[r] * ((float)CELLS / MAXO));
        cell = min(cell, CELLS - 1);
        p[r] = lut[2 * cell];
        q[r] = lut[2 * cell + 1];
    }

    float res[R * 3];
#pragma unroll
    for (int r = 0; r < R; r++) {
        const float oo = o[r];
        const float l0 = fmaf(oo, p[r].y, p[r].x);
        const float l1 = fmaf(oo, p[r].w, p[r].z);
        const float l2 = fmaf(oo, q[r].y, q[r].x);
        const float m  = fmaxf(l0, fmaxf(l1, l2));
        const float e0 = __expf(l0 - m);
        const float e1 = __expf(l1 - m);
        const float e2 = __expf(l2 - m);
        const float inv = __builtin_amdgcn_rcpf(e0 + e1 + e2);
        float p0 = e0 * inv, p1 = e1 * inv, p2 = e2 * inv;
        if (oo >= 100.0f) {
            p0 = 0.f; p1 = 0.f; p2 = 1.f;
        } else if (oo <= 10.0f) {
            const float inv12 = __builtin_amdgcn_rcpf(e0 + e1);
            p0 = e0 * inv12; p1 = e1 * inv12; p2 = 0.f;
        }
        res[3 * r + 0] = p0; res[3 * r + 1] = p1; res[3 * r + 2] = p2;
    }

    // 12 contiguous floats per thread = 3 float4 stores (48B-aligned base)
    float4* outp = (float4*)(out + base * 3);
#pragma unroll
    for (int i = 0; i < 3; i++)
        outp[i] = make_float4(res[4 * i], res[4 * i + 1], res[4 * i + 2], res[4 * i + 3]);
}

// ---- Fallback (exact direct evaluation) if d_ws is too small for the LUT ----
__global__ __launch_bounds__(BLOCK) void gating_direct_kernel(
    const float* __restrict__ o_batch,
    const float* __restrict__ W1, const float* __restrict__ b1,
    const float* __restrict__ W2, const float* __restrict__ b2,
    float* __restrict__ out)
{
    __shared__ float2 s_wb[HIDDEN];
    __shared__ float4 s_w2[HIDDEN];
    const int tid = threadIdx.x;
    if (tid < HIDDEN) {
        s_wb[tid] = make_float2(W1[tid], b1[tid]);
        s_w2[tid] = make_float4(W2[3 * tid], W2[3 * tid + 1], W2[3 * tid + 2], 0.f);
    }
    const float bb0 = b2[0], bb1 = b2[1], bb2 = b2[2];
    __syncthreads();

    const long long base =
        (long long)blockIdx.x * (BLOCK * R) + (long long)tid * R;
    const float4 o4 = *(const float4*)(o_batch + base);
    const float o[R] = {o4.x, o4.y, o4.z, o4.w};

    float x[R], a0[R], a1[R], a2[R];
#pragma unroll
    for (int r = 0; r < R; r++) {
        x[r] = o[r] * (1.0f / 150.0f);
        a0[r] = bb0; a1[r] = bb1; a2[r] = bb2;
    }
#pragma unroll 8
    for (int j = 0; j < HIDDEN; j++) {
        const float2 wb = s_wb[j];
        const float4 w2 = s_w2[j];
#pragma unroll
        for (int r = 0; r < R; r++) {
            const float h = fmaxf(fmaf(x[r], wb.x, wb.y), 0.0f);
            a0[r] = fmaf(h, w2.x, a0[r]);
            a1[r] = fmaf(h, w2.y, a1[r]);
            a2[r] = fmaf(h, w2.z, a2[r]);
        }
    }
    float res[R * 3];
#pragma unroll
    for (int r = 0; r < R; r++) {
        const float m  = fmaxf(a0[r], fmaxf(a1[r], a2[r]));
        const float e0 = __expf(a0[r] - m);
        const float e1 = __expf(a1[r] - m);
        const float e2 = __expf(a2[r] - m);
        const float inv = __builtin_amdgcn_rcpf(e0 + e1 + e2);
        float p0 = e0 * inv, p1 = e1 * inv, p2 = e2 * inv;
        const float oo = o[r];
        if (oo >= 100.0f) { p0 = 0.f; p1 = 0.f; p2 = 1.f; }
        else if (oo <= 10.0f) {
            const float inv12 = __builtin_amdgcn_rcpf(e0 + e1);
            p0 = e0 * inv12; p1 = e1 * inv12; p2 = 0.f;
        }
        res[3 * r + 0] = p0; res[3 * r + 1] = p1; res[3 * r + 2] = p2;
    }
    float4* outp = (float4*)(out + base * 3);
#pragma unroll
    for (int i = 0; i < 3; i++)
        outp[i] = make_float4(res[4 * i], res[4 * i + 1], res[4 * i + 2], res[4 * i + 3]);
}

extern "C" void kernel_launch(void* const* d_in, const int* in_sizes, int n_in,
                              void* d_out, int out_size, void* d_ws, size_t ws_size,
                              hipStream_t stream) {
    const float* o_batch = (const float*)d_in[0];
    const float* W1      = (const float*)d_in[1];
    const float* b1      = (const float*)d_in[2];
    const float* W2      = (const float*)d_in[3];
    const float* b2      = (const float*)d_in[4];
    float* out = (float*)d_out;

    const int batch = in_sizes[0];            // 2097152
    const int grid  = batch / (BLOCK * R);    // 2048

    const size_t lut_bytes = (size_t)CELLS * 2 * sizeof(float4);  // 128 KB
    if (ws_size >= lut_bytes) {
        float4* lut = (float4*)d_ws;
        build_lut_kernel<<<CELLS / 256, 256, 0, stream>>>(W1, b1, W2, b2, lut);
        gating_lut_kernel<<<grid, BLOCK, 0, stream>>>(o_batch, lut, out);
    } else {
        gating_direct_kernel<<<grid, BLOCK, 0, stream>>>(o_batch, W1, b1, W2, b2, out);
    }
}

// Round 3
// 82.502 us; speedup vs baseline: 1.1140x; 1.1140x over previous
//
#include <hip/hip_runtime.h>

// GatingRouting, fully fused single kernel.
//
// logit_k(o) = b2_k + sum_j relu(w1_j*o/150 + b1_j)*W2[j,k] is piecewise
// LINEAR in o (<=64 breakpoints over [0,150]). Each block builds a 256-cell
// line-coefficient LUT in LDS (1 cell/thread, 64-iter loop with uniform
// addresses -> scalar loads), then evaluates 4096 rows from it.
// Cell halfwidth 0.293 (o units) -> worst-case logit err |w1*W2|/150*0.293
// ~ 4e-3 -> output err ~2e-3, 10x under the 2e-2 threshold.
//
// Blend: o>=100 -> (0,0,1); o<=10 -> (e0,e1,0)/(e0+e1); else softmax.

#define HIDDEN 64
constexpr int   CELLS = 256;    // LDS LUT cells (one per thread)
constexpr int   BLOCK = 256;
constexpr int   R     = 16;     // rows per thread -> 4096 rows/block
constexpr float MAXO  = 150.0f;

__global__ __launch_bounds__(BLOCK) void gating_fused_kernel(
    const float* __restrict__ o_batch,
    const float* __restrict__ W1, const float* __restrict__ b1,
    const float* __restrict__ W2,   // (64,3) row-major
    const float* __restrict__ b2,   // (3,)
    float* __restrict__ out)        // (BATCH,3) row-major
{
    __shared__ float4 sA[CELLS];  // (c0, d0, c1, d1)
    __shared__ float4 sB[CELLS];  // (c2, d2, 0, 0)

    const int tid = threadIdx.x;

    // ---- Phase 1: build this block's LUT cell (tid == cell) ----
    {
        const float oc = ((float)tid + 0.5f) * (MAXO / (float)CELLS);
        const float x  = oc * (1.0f / MAXO);
        float c0 = b2[0], c1 = b2[1], c2 = b2[2];
        float d0 = 0.f,   d1 = 0.f,   d2 = 0.f;
#pragma unroll 8
        for (int j = 0; j < HIDDEN; j++) {
            const float w    = W1[j];          // uniform addr -> s_load
            const float b    = b1[j];
            const float pre  = fmaf(x, w, b);
            const float mask = pre > 0.0f ? 1.0f : 0.0f;
            const float bm   = b * mask;
            const float wm   = w * (mask * (1.0f / MAXO));  // slope per unit o
            const float w20 = W2[3 * j], w21 = W2[3 * j + 1], w22 = W2[3 * j + 2];
            c0 = fmaf(bm, w20, c0);  d0 = fmaf(wm, w20, d0);
            c1 = fmaf(bm, w21, c1);  d1 = fmaf(wm, w21, d1);
            c2 = fmaf(bm, w22, c2);  d2 = fmaf(wm, w22, d2);
        }
        sA[tid] = make_float4(c0, d0, c1, d1);
        sB[tid] = make_float4(c2, d2, 0.f, 0.f);
    }
    __syncthreads();

    // ---- Phase 2: evaluate R rows in 4 groups of 4 (register-light) ----
    const long long block_base = (long long)blockIdx.x * (BLOCK * R);

#pragma unroll
    for (int g = 0; g < R / 4; g++) {
        // group-interleaved: lane-stride 16 B -> perfectly coalesced loads
        const long long base = block_base + (long long)g * (BLOCK * 4) + (long long)tid * 4;
        const float4 o4 = *(const float4*)(o_batch + base);
        const float o[4] = {o4.x, o4.y, o4.z, o4.w};

        float4 pA[4], pB[4];
#pragma unroll
        for (int r = 0; r < 4; r++) {
            int cell = (int)(o[r] * ((float)CELLS / MAXO));
            cell = min(max(cell, 0), CELLS - 1);
            pA[r] = sA[cell];
            pB[r] = sB[cell];
        }

        float res[12];
#pragma unroll
        for (int r = 0; r < 4; r++) {
            const float oo = o[r];
            const float l0 = fmaf(oo, pA[r].y, pA[r].x);
            const float l1 = fmaf(oo, pA[r].w, pA[r].z);
            const float l2 = fmaf(oo, pB[r].y, pB[r].x);
            const float m  = fmaxf(l0, fmaxf(l1, l2));
            const float e0 = __expf(l0 - m);
            const float e1 = __expf(l1 - m);
            const float e2 = __expf(l2 - m);
            const float inv = __builtin_amdgcn_rcpf(e0 + e1 + e2);
            float p0 = e0 * inv, p1 = e1 * inv, p2 = e2 * inv;
            if (oo >= 100.0f) {
                p0 = 0.f; p1 = 0.f; p2 = 1.f;
            } else if (oo <= 10.0f) {
                const float inv12 = __builtin_amdgcn_rcpf(e0 + e1);
                p0 = e0 * inv12; p1 = e1 * inv12; p2 = 0.f;
            }
            res[3 * r + 0] = p0; res[3 * r + 1] = p1; res[3 * r + 2] = p2;
        }

        float4* outp = (float4*)(out + base * 3);
        outp[0] = make_float4(res[0], res[1], res[2],  res[3]);
        outp[1] = make_float4(res[4], res[5], res[6],  res[7]);
        outp[2] = make_float4(res[8], res[9], res[10], res[11]);
    }
}

extern "C" void kernel_launch(void* const* d_in, const int* in_sizes, int n_in,
                              void* d_out, int out_size, void* d_ws, size_t ws_size,
                              hipStream_t stream) {
    const float* o_batch = (const float*)d_in[0];
    const float* W1      = (const float*)d_in[1];
    const float* b1      = (const float*)d_in[2];
    const float* W2      = (const float*)d_in[3];
    const float* b2      = (const float*)d_in[4];
    float* out = (float*)d_out;

    const int batch = in_sizes[0];            // 2097152
    const int grid  = batch / (BLOCK * R);    // 512
    gating_fused_kernel<<<grid, BLOCK, 0, stream>>>(o_batch, W1, b1, W2, b2, out);
}